// Round 13
// baseline (517.680 us; speedup 1.0000x reference)
//
#include <hip/hip_runtime.h>

#define N_NODESC 100000
#define N_EDGESC 600000
#define HDIM 128
#define H3 384
#define NUM_STEPSC 5

#define SCAN_BLOCK 256
#define SCAN_CHUNK 1024

#define GRU_M 32
#define NT_TILES (N_NODESC / GRU_M)   // 3125
#define PERSIST_GRID 256

typedef __attribute__((ext_vector_type(8))) short bf16x8;
typedef __attribute__((ext_vector_type(4))) float f32x4;

__device__ __forceinline__ unsigned short f2bf(float x) {
    union { float f; unsigned int u; } v; v.f = x;
    unsigned int r = v.u + 0x7FFF + ((v.u >> 16) & 1);
    return (unsigned short)(r >> 16);
}
__device__ __forceinline__ float bf2f(unsigned short lo16) {
    union { unsigned int u; float f; } v; v.u = (unsigned int)lo16 << 16; return v.f;
}

// hardware gates: v_exp_f32 computes 2^x, v_rcp_f32 ~1ulp. Saturation at +/-inf is exact.
__device__ __forceinline__ float fast_sigmoid(float x) {
    float e = __builtin_amdgcn_exp2f(-1.44269504f * x);
    return __builtin_amdgcn_rcpf(1.0f + e);
}
__device__ __forceinline__ float fast_tanh(float x) {
    float e = __builtin_amdgcn_exp2f(2.88539008f * x);
    return 1.0f - 2.0f * __builtin_amdgcn_rcpf(1.0f + e);
}

// ---- weight prep: W_c = W_ih @ W_msg (fused), pack W_c and W_hh^T into MFMA B-frag layout ----
__global__ void prep_pack(const float* __restrict__ W_msg, const float* __restrict__ b_msg,
                          const float* __restrict__ W_ih, const float* __restrict__ W_hh,
                          unsigned short* __restrict__ Wc, unsigned short* __restrict__ Wh,
                          float* __restrict__ b_c)
{
    int tid = blockIdx.x * blockDim.x + threadIdx.x;
    if (tid >= HDIM * H3) return;
    int j = tid % H3;   // output col 0..383
    int k = tid / H3;   // input dim 0..127
    float wc = 0.f;
    for (int m = 0; m < HDIM; ++m)
        wc = fmaf(W_ih[j*HDIM + m], W_msg[m*HDIM + k], wc);
    float wh = W_hh[j*HDIM + k];
    int kt = k >> 5, kk = k & 31, jt = j >> 4, jj = j & 15;
    int lane = ((kk >> 3) << 4) + jj;
    int e = kk & 7;
    size_t idx = ((size_t)(kt*24 + jt)*64 + lane)*8 + e;
    Wc[idx] = f2bf(wc);
    Wh[idx] = f2bf(wh);
    if (k == 0) {
        float bb = 0.f;
        for (int m = 0; m < HDIM; ++m) bb = fmaf(W_ih[j*HDIM + m], b_msg[m], bb);
        b_c[j] = bb;
    }
}

// ---- h_bf init: bf16 shadow of x ----
__global__ void init_hbf(const float* __restrict__ x, unsigned short* __restrict__ h_bf)
{
    int i = blockIdx.x * blockDim.x + threadIdx.x;
    if (i >= N_NODESC * HDIM / 4) return;
    float4 v = ((const float4*)x)[i];
    ushort4 b;
    b.x = f2bf(v.x); b.y = f2bf(v.y); b.z = f2bf(v.z); b.w = f2bf(v.w);
    ((ushort4*)h_bf)[i] = b;
}

// ---- CSR build ----
__global__ void hist_kernel(const int* __restrict__ eidx, int* __restrict__ deg)
{
    int e = blockIdx.x * blockDim.x + threadIdx.x;
    if (e < N_EDGESC) atomicAdd(&deg[eidx[e]], 1);
}

__global__ void scan_partial(const int* __restrict__ in, int* __restrict__ out,
                             int* __restrict__ bsums, int n)
{
    __shared__ int ts[SCAN_BLOCK];
    int tid = threadIdx.x;
    int base = blockIdx.x * SCAN_CHUNK + tid * 4;
    int v0 = (base+0 < n) ? in[base+0] : 0;
    int v1 = (base+1 < n) ? in[base+1] : 0;
    int v2 = (base+2 < n) ? in[base+2] : 0;
    int v3 = (base+3 < n) ? in[base+3] : 0;
    ts[tid] = v0+v1+v2+v3;
    __syncthreads();
    for (int off = 1; off < SCAN_BLOCK; off <<= 1) {
        int t = (tid >= off) ? ts[tid-off] : 0;
        __syncthreads();
        ts[tid] += t;
        __syncthreads();
    }
    int excl = (tid > 0) ? ts[tid-1] : 0;
    if (tid == SCAN_BLOCK-1) bsums[blockIdx.x] = ts[SCAN_BLOCK-1];
    if (base+0 < n) out[base+0] = excl;
    if (base+1 < n) out[base+1] = excl + v0;
    if (base+2 < n) out[base+2] = excl + v0 + v1;
    if (base+3 < n) out[base+3] = excl + v0 + v1 + v2;
}

__global__ void scan_sums(int* bsums, int nb)
{
    if (threadIdx.x == 0 && blockIdx.x == 0) {
        int run = 0;
        for (int b = 0; b < nb; ++b) { int t = bsums[b]; bsums[b] = run; run += t; }
    }
}

// also seeds the scatter cursor
__global__ void scan_add(int* __restrict__ out, const int* __restrict__ bsums, int n,
                         int* __restrict__ cur)
{
    int i = blockIdx.x * blockDim.x + threadIdx.x;
    if (i < n) {
        int v = out[i] + bsums[i / SCAN_CHUNK];
        out[i] = v;
        if (i < N_NODESC) cur[i] = v;
    }
}

__global__ void scatter_edges(const int* __restrict__ eidx, int* __restrict__ cur,
                              int* __restrict__ cols)
{
    int e = blockIdx.x * blockDim.x + threadIdx.x;
    if (e < N_EDGESC) {
        int r = eidx[e];
        int c = eidx[N_EDGESC + e];
        int p = atomicAdd(&cur[r], 1);
        cols[p] = c;
    }
}

// ---- fused step: persistent blocks + register weights + row-parallel gather + MFMA + GRU ----
// grid = 256 (1 block/CU), each block strides over 3125 tiles of 32 nodes.
// Weight B-frags (24 x bf16x8 = 96 VGPR/lane) and biases loaded ONCE per block:
// kills the 600 MB/step of per-block weight re-reads from L2 (round-11/12 marginal
// L2 cost ~72 GB/us). Tile body = round-11 structure (best measured).
__global__ __launch_bounds__(512, 2) void gnn_step(
    const unsigned short* __restrict__ hb_src, unsigned short* __restrict__ hb_dst,
    float* __restrict__ h_out,
    const int* __restrict__ offs, const int* __restrict__ cols,
    const unsigned short* __restrict__ Wc, const unsigned short* __restrict__ Wh,
    const float* __restrict__ b_c, const float* __restrict__ b_ih, const float* __restrict__ b_hh)
{
    __shared__ __align__(16) unsigned short LB[2 * GRU_M * HDIM];  // [Sl | Hl], 16 KB
    unsigned short* Sl = LB;
    unsigned short* Hl = LB + GRU_M * HDIM;
    __shared__ float Dl[GRU_M];

    int tid = threadIdx.x;
    int lane = tid & 63;
    int wid  = tid >> 6;       // 0..7 -> col tile
    int kg   = lane >> 4;      // 0..3
    int lr   = lane & 15;
    int c    = (wid << 4) + lr;

    int srow = tid >> 4;             // 0..31: node-local row
    int cb   = (tid & 15) << 4;      // byte col within 256B row
    int pb   = srow*256 + (cb ^ ((srow & 7) << 4));

    // hoisted per-column constants
    float bc_r = b_c[c],  bc_z = b_c[c+128],  bc_n = b_c[c+256];
    float bs_r = b_ih[c]     + b_hh[c];
    float bs_z = b_ih[c+128] + b_hh[c+128];
    float bi_n = b_ih[c+256], bh_n = b_hh[c+256];

    // hoisted weight B-fragments: this wave's wid slice only (96 VGPR)
    bf16x8 wcr[4], wcz[4], wcn[4], whr[4], whz[4], whn[4];
    #pragma unroll
    for (int kc = 0; kc < 4; ++kc) {
        const bf16x8* Bc = (const bf16x8*)Wc + (size_t)kc*1536 + lane;
        const bf16x8* Bh = (const bf16x8*)Wh + (size_t)kc*1536 + lane;
        wcr[kc] = Bc[(size_t)(wid     ) * 64];
        wcz[kc] = Bc[(size_t)(wid +  8) * 64];
        wcn[kc] = Bc[(size_t)(wid + 16) * 64];
        whr[kc] = Bh[(size_t)(wid     ) * 64];
        whz[kc] = Bh[(size_t)(wid +  8) * 64];
        whn[kc] = Bh[(size_t)(wid + 16) * 64];
    }

    int r0 = lr, r1 = 16 + lr;
    int x0 = (r0 & 7) << 4, x1 = (r1 & 7) << 4;

    for (int tile = blockIdx.x; tile < NT_TILES; tile += PERSIST_GRID) {
        int i0 = tile * GRU_M;

        // own rows -> Hl (feeds Wh GEMM + carry)
        *(float4*)((char*)Hl + pb) =
            *(const float4*)((const char*)hb_src + (size_t)(i0 + srow)*256 + cb);

        // row-parallel gather, 4-deep unroll for MLP
        int beg = offs[i0 + srow], end = offs[i0 + srow + 1];
        float acc[8] = {0.f,0.f,0.f,0.f,0.f,0.f,0.f,0.f};
        int e = beg;
        for (; e + 3 < end; e += 4) {
            int s0 = cols[e+0], s1 = cols[e+1], s2 = cols[e+2], s3 = cols[e+3];
            bf16x8 v0 = *(const bf16x8*)((const char*)hb_src + (size_t)s0*256 + cb);
            bf16x8 v1 = *(const bf16x8*)((const char*)hb_src + (size_t)s1*256 + cb);
            bf16x8 v2 = *(const bf16x8*)((const char*)hb_src + (size_t)s2*256 + cb);
            bf16x8 v3 = *(const bf16x8*)((const char*)hb_src + (size_t)s3*256 + cb);
            #pragma unroll
            for (int j = 0; j < 8; ++j) {
                float t0 = bf2f((unsigned short)v0[j]) + bf2f((unsigned short)v1[j]);
                float t1 = bf2f((unsigned short)v2[j]) + bf2f((unsigned short)v3[j]);
                acc[j] += t0 + t1;
            }
        }
        if (e + 1 < end) {
            int s0 = cols[e], s1 = cols[e+1];
            bf16x8 v0 = *(const bf16x8*)((const char*)hb_src + (size_t)s0*256 + cb);
            bf16x8 v1 = *(const bf16x8*)((const char*)hb_src + (size_t)s1*256 + cb);
            #pragma unroll
            for (int j = 0; j < 8; ++j)
                acc[j] += bf2f((unsigned short)v0[j]) + bf2f((unsigned short)v1[j]);
            e += 2;
        }
        if (e < end) {
            bf16x8 v0 = *(const bf16x8*)((const char*)hb_src + (size_t)cols[e]*256 + cb);
            #pragma unroll
            for (int j = 0; j < 8; ++j) acc[j] += bf2f((unsigned short)v0[j]);
        }
        {
            union { ushort2 u2[4]; float4 f4; } pk;
            #pragma unroll
            for (int j = 0; j < 4; ++j) {
                pk.u2[j].x = f2bf(acc[2*j]);
                pk.u2[j].y = f2bf(acc[2*j+1]);
            }
            *(float4*)((char*)Sl + pb) = pk.f4;
        }
        if ((tid & 15) == 0) Dl[srow] = (float)(end - beg);
        __syncthreads();

        f32x4 a_cr[2], a_cz[2], a_cn[2], a_hr[2], a_hz[2], a_hn[2];
        #pragma unroll
        for (int t = 0; t < 2; ++t) {
            a_cr[t] = (f32x4){0,0,0,0}; a_cz[t] = (f32x4){0,0,0,0}; a_cn[t] = (f32x4){0,0,0,0};
            a_hr[t] = (f32x4){0,0,0,0}; a_hz[t] = (f32x4){0,0,0,0}; a_hn[t] = (f32x4){0,0,0,0};
        }

        #pragma unroll
        for (int kc = 0; kc < 4; ++kc) {
            int cbk = kc*64 + kg*16;
            bf16x8 aS0 = *(const bf16x8*)((const char*)Sl + r0*256 + (cbk ^ x0));
            bf16x8 aS1 = *(const bf16x8*)((const char*)Sl + r1*256 + (cbk ^ x1));
            bf16x8 aH0 = *(const bf16x8*)((const char*)Hl + r0*256 + (cbk ^ x0));
            bf16x8 aH1 = *(const bf16x8*)((const char*)Hl + r1*256 + (cbk ^ x1));
            a_cr[0] = __builtin_amdgcn_mfma_f32_16x16x32_bf16(aS0, wcr[kc], a_cr[0], 0, 0, 0);
            a_cr[1] = __builtin_amdgcn_mfma_f32_16x16x32_bf16(aS1, wcr[kc], a_cr[1], 0, 0, 0);
            a_cz[0] = __builtin_amdgcn_mfma_f32_16x16x32_bf16(aS0, wcz[kc], a_cz[0], 0, 0, 0);
            a_cz[1] = __builtin_amdgcn_mfma_f32_16x16x32_bf16(aS1, wcz[kc], a_cz[1], 0, 0, 0);
            a_cn[0] = __builtin_amdgcn_mfma_f32_16x16x32_bf16(aS0, wcn[kc], a_cn[0], 0, 0, 0);
            a_cn[1] = __builtin_amdgcn_mfma_f32_16x16x32_bf16(aS1, wcn[kc], a_cn[1], 0, 0, 0);
            a_hr[0] = __builtin_amdgcn_mfma_f32_16x16x32_bf16(aH0, whr[kc], a_hr[0], 0, 0, 0);
            a_hr[1] = __builtin_amdgcn_mfma_f32_16x16x32_bf16(aH1, whr[kc], a_hr[1], 0, 0, 0);
            a_hz[0] = __builtin_amdgcn_mfma_f32_16x16x32_bf16(aH0, whz[kc], a_hz[0], 0, 0, 0);
            a_hz[1] = __builtin_amdgcn_mfma_f32_16x16x32_bf16(aH1, whz[kc], a_hz[1], 0, 0, 0);
            a_hn[0] = __builtin_amdgcn_mfma_f32_16x16x32_bf16(aH0, whn[kc], a_hn[0], 0, 0, 0);
            a_hn[1] = __builtin_amdgcn_mfma_f32_16x16x32_bf16(aH1, whn[kc], a_hn[1], 0, 0, 0);
        }

        float hv[2][4];
        #pragma unroll
        for (int t = 0; t < 2; ++t) {
            #pragma unroll
            for (int q = 0; q < 4; ++q) {
                int row = t*16 + (kg << 2) + q;
                float dg = Dl[row];
                float r  = fast_sigmoid(a_cr[t][q] + a_hr[t][q] + fmaf(dg, bc_r, bs_r));
                float z  = fast_sigmoid(a_cz[t][q] + a_hz[t][q] + fmaf(dg, bc_z, bs_z));
                float gin = a_cn[t][q] + fmaf(dg, bc_n, bi_n);
                float ghn = a_hn[t][q] + bh_n;
                float nn = fast_tanh(fmaf(r, ghn, gin));
                float hold = bf2f(*(const unsigned short*)((const char*)Hl + row*256 + ((c*2) ^ ((row & 7) << 4))));
                hv[t][q] = fmaf(z, hold - nn, nn);
            }
        }
        __syncthreads();   // all MFMA/carry reads of Sl,Hl complete before overwrite

        if (!h_out) {
            // bf16 state: stage into Sl (swizzled), then coalesced float4 rows
            #pragma unroll
            for (int t = 0; t < 2; ++t)
                #pragma unroll
                for (int q = 0; q < 4; ++q) {
                    int row = t*16 + (kg << 2) + q;
                    *(unsigned short*)((char*)Sl + row*256 + ((c*2) ^ ((row & 7) << 4))) = f2bf(hv[t][q]);
                }
            __syncthreads();
            *(float4*)((char*)hb_dst + (size_t)(i0 + srow)*256 + cb) =
                *(const float4*)((const char*)Sl + pb);
        } else {
            // final step: fp32 output only. Stage 32x128 f32 = 16 KB into LB.
            float* F = (float*)LB;
            #pragma unroll
            for (int t = 0; t < 2; ++t)
                #pragma unroll
                for (int q = 0; q < 4; ++q) {
                    int row = t*16 + (kg << 2) + q;
                    *(float*)((char*)F + row*512 + ((c*4) ^ ((row & 7) << 4))) = hv[t][q];
                }
            __syncthreads();
            int sr2 = tid >> 5;              // 0..15
            int cb2 = (tid & 31) << 4;       // byte within 512B fp32 row
            #pragma unroll
            for (int half = 0; half < 2; ++half) {
                int rr = half*16 + sr2;
                float4 v = *(const float4*)((const char*)F + rr*512 + (cb2 ^ ((rr & 7) << 4)));
                *(float4*)((char*)h_out + (size_t)(i0 + rr)*512 + cb2) = v;
            }
        }
        __syncthreads();   // stores done before next tile's LDS writes
    }
}

extern "C" void kernel_launch(void* const* d_in, const int* in_sizes, int n_in,
                              void* d_out, int out_size, void* d_ws, size_t ws_size,
                              hipStream_t stream)
{
    const float* x     = (const float*)d_in[0];
    const int*   eidx  = (const int*)d_in[1];
    const float* W_msg = (const float*)d_in[2];
    const float* b_msg = (const float*)d_in[3];
    const float* W_ih  = (const float*)d_in[4];
    const float* W_hh  = (const float*)d_in[5];
    const float* b_ih  = (const float*)d_in[6];
    const float* b_hh  = (const float*)d_in[7];

    float* h = (float*)d_out;

    char* ws = (char*)d_ws;
    size_t off = 0;
    auto alloc = [&](size_t bytes) -> void* {
        void* p = ws + off;
        off = (off + bytes + 255) & ~(size_t)255;
        return p;
    };
    unsigned short* hb0 = (unsigned short*)alloc((size_t)N_NODESC*HDIM*sizeof(unsigned short));
    unsigned short* hb1 = (unsigned short*)alloc((size_t)N_NODESC*HDIM*sizeof(unsigned short));
    unsigned short* Wc  = (unsigned short*)alloc((size_t)HDIM*H3*sizeof(unsigned short));
    unsigned short* Wh  = (unsigned short*)alloc((size_t)HDIM*H3*sizeof(unsigned short));
    float* b_c    = (float*)alloc(H3*sizeof(float));
    int*   deg    = (int*)alloc((N_NODESC+1)*sizeof(int));
    int*   offs   = (int*)alloc((N_NODESC+1)*sizeof(int));
    int*   cur    = (int*)alloc(N_NODESC*sizeof(int));
    int*   cols   = (int*)alloc(N_EDGESC*sizeof(int));
    int*   bsums  = (int*)alloc(256*sizeof(int));

    hipMemsetAsync(deg, 0, (N_NODESC+1)*sizeof(int), stream);

    init_hbf<<<(N_NODESC*HDIM/4 + 255)/256, 256, 0, stream>>>(x, hb0);
    prep_pack<<<(HDIM*H3 + 255)/256, 256, 0, stream>>>(W_msg, b_msg, W_ih, W_hh, Wc, Wh, b_c);

    hist_kernel<<<(N_EDGESC + 255)/256, 256, 0, stream>>>(eidx, deg);

    int n_scan = N_NODESC + 1;
    int nb = (n_scan + SCAN_CHUNK - 1) / SCAN_CHUNK;
    scan_partial<<<nb, SCAN_BLOCK, 0, stream>>>(deg, offs, bsums, n_scan);
    scan_sums<<<1, 64, 0, stream>>>(bsums, nb);
    scan_add<<<(n_scan + 255)/256, 256, 0, stream>>>(offs, bsums, n_scan, cur);

    scatter_edges<<<(N_EDGESC + 255)/256, 256, 0, stream>>>(eidx, cur, cols);

    for (int step = 0; step < NUM_STEPSC; ++step) {
        const unsigned short* src = (step & 1) ? hb1 : hb0;
        unsigned short*       dst = (step & 1) ? hb0 : hb1;
        float* out = (step == NUM_STEPSC - 1) ? h : nullptr;
        gnn_step<<<PERSIST_GRID, 512, 0, stream>>>(src, dst, out, offs, cols,
                                                   Wc, Wh, b_c, b_ih, b_hh);
    }
}

// Round 14
// 427.888 us; speedup vs baseline: 1.2098x; 1.2098x over previous
//
#include <hip/hip_runtime.h>

#define N_NODESC 100000
#define N_EDGESC 600000
#define HDIM 128
#define H3 384
#define NUM_STEPSC 5

#define SCAN_BLOCK 256
#define SCAN_CHUNK 1024

typedef __attribute__((ext_vector_type(8))) short bf16x8;
typedef __attribute__((ext_vector_type(4))) float f32x4;

__device__ __forceinline__ unsigned short f2bf(float x) {
    union { float f; unsigned int u; } v; v.f = x;
    unsigned int r = v.u + 0x7FFF + ((v.u >> 16) & 1);
    return (unsigned short)(r >> 16);
}
__device__ __forceinline__ float bf2f(unsigned short lo16) {
    union { unsigned int u; float f; } v; v.u = (unsigned int)lo16 << 16; return v.f;
}

// hardware gates: v_exp_f32 computes 2^x, v_rcp_f32 ~1ulp. Saturation at +/-inf is exact.
__device__ __forceinline__ float fast_sigmoid(float x) {
    float e = __builtin_amdgcn_exp2f(-1.44269504f * x);
    return __builtin_amdgcn_rcpf(1.0f + e);
}
__device__ __forceinline__ float fast_tanh(float x) {
    float e = __builtin_amdgcn_exp2f(2.88539008f * x);
    return 1.0f - 2.0f * __builtin_amdgcn_rcpf(1.0f + e);
}

// ---- weight prep: W_c = W_ih @ W_msg (fused), pack W_c and W_hh^T into MFMA B-frag layout ----
__global__ void prep_pack(const float* __restrict__ W_msg, const float* __restrict__ b_msg,
                          const float* __restrict__ W_ih, const float* __restrict__ W_hh,
                          unsigned short* __restrict__ Wc, unsigned short* __restrict__ Wh,
                          float* __restrict__ b_c)
{
    int tid = blockIdx.x * blockDim.x + threadIdx.x;
    if (tid >= HDIM * H3) return;
    int j = tid % H3;   // output col 0..383
    int k = tid / H3;   // input dim 0..127
    float wc = 0.f;
    for (int m = 0; m < HDIM; ++m)
        wc = fmaf(W_ih[j*HDIM + m], W_msg[m*HDIM + k], wc);
    float wh = W_hh[j*HDIM + k];
    int kt = k >> 5, kk = k & 31, jt = j >> 4, jj = j & 15;
    int lane = ((kk >> 3) << 4) + jj;
    int e = kk & 7;
    size_t idx = ((size_t)(kt*24 + jt)*64 + lane)*8 + e;
    Wc[idx] = f2bf(wc);
    Wh[idx] = f2bf(wh);
    if (k == 0) {
        float bb = 0.f;
        for (int m = 0; m < HDIM; ++m) bb = fmaf(W_ih[j*HDIM + m], b_msg[m], bb);
        b_c[j] = bb;
    }
}

// ---- h_bf init: bf16 shadow of x ----
__global__ void init_hbf(const float* __restrict__ x, unsigned short* __restrict__ h_bf)
{
    int i = blockIdx.x * blockDim.x + threadIdx.x;
    if (i >= N_NODESC * HDIM / 4) return;
    float4 v = ((const float4*)x)[i];
    ushort4 b;
    b.x = f2bf(v.x); b.y = f2bf(v.y); b.z = f2bf(v.z); b.w = f2bf(v.w);
    ((ushort4*)h_bf)[i] = b;
}

// ---- CSR build ----
__global__ void hist_kernel(const int* __restrict__ eidx, int* __restrict__ deg)
{
    int e = blockIdx.x * blockDim.x + threadIdx.x;
    if (e < N_EDGESC) atomicAdd(&deg[eidx[e]], 1);
}

__global__ void scan_partial(const int* __restrict__ in, int* __restrict__ out,
                             int* __restrict__ bsums, int n)
{
    __shared__ int ts[SCAN_BLOCK];
    int tid = threadIdx.x;
    int base = blockIdx.x * SCAN_CHUNK + tid * 4;
    int v0 = (base+0 < n) ? in[base+0] : 0;
    int v1 = (base+1 < n) ? in[base+1] : 0;
    int v2 = (base+2 < n) ? in[base+2] : 0;
    int v3 = (base+3 < n) ? in[base+3] : 0;
    ts[tid] = v0+v1+v2+v3;
    __syncthreads();
    for (int off = 1; off < SCAN_BLOCK; off <<= 1) {
        int t = (tid >= off) ? ts[tid-off] : 0;
        __syncthreads();
        ts[tid] += t;
        __syncthreads();
    }
    int excl = (tid > 0) ? ts[tid-1] : 0;
    if (tid == SCAN_BLOCK-1) bsums[blockIdx.x] = ts[SCAN_BLOCK-1];
    if (base+0 < n) out[base+0] = excl;
    if (base+1 < n) out[base+1] = excl + v0;
    if (base+2 < n) out[base+2] = excl + v0 + v1;
    if (base+3 < n) out[base+3] = excl + v0 + v1 + v2;
}

__global__ void scan_sums(int* bsums, int nb)
{
    if (threadIdx.x == 0 && blockIdx.x == 0) {
        int run = 0;
        for (int b = 0; b < nb; ++b) { int t = bsums[b]; bsums[b] = run; run += t; }
    }
}

// also seeds the scatter cursor
__global__ void scan_add(int* __restrict__ out, const int* __restrict__ bsums, int n,
                         int* __restrict__ cur)
{
    int i = blockIdx.x * blockDim.x + threadIdx.x;
    if (i < n) {
        int v = out[i] + bsums[i / SCAN_CHUNK];
        out[i] = v;
        if (i < N_NODESC) cur[i] = v;
    }
}

__global__ void scatter_edges(const int* __restrict__ eidx, int* __restrict__ cur,
                              int* __restrict__ cols)
{
    int e = blockIdx.x * blockDim.x + threadIdx.x;
    if (e < N_EDGESC) {
        int r = eidx[e];
        int c = eidx[N_EDGESC + e];
        int p = atomicAdd(&cur[r], 1);
        cols[p] = c;
    }
}

// ---- fused step: row-parallel gather (4-deep MLP) + dual MFMA GEMM + GRU gates ----
// 512 threads = 8 waves, 32 nodes/block. Best measured config (R11: 72.6 us/step).
// Phase 1: stage own rows -> Hl; per-row gather with 4 independent row-loads in flight.
// Phase 2: dual MFMA GEMMs; gate math register-local in C-layout
//          (col=lane&15, row=(lane>>4)*4+q).
// Phase 3: restage outputs through LDS -> coalesced float4 stores (no partial-line RMW).
// Ledger: LDS-atomic gather 6x WORSE (R10); GRU_M=16 2x-occupancy worse via 2x weight
// L2 traffic (R12); persistent+reg-weights worse via occupancy collapse (R13).
#define GRU_M 32
__global__ __launch_bounds__(512) void gnn_step(
    const unsigned short* __restrict__ hb_src, unsigned short* __restrict__ hb_dst,
    float* __restrict__ h_out,
    const int* __restrict__ offs, const int* __restrict__ cols,
    const unsigned short* __restrict__ Wc, const unsigned short* __restrict__ Wh,
    const float* __restrict__ b_c, const float* __restrict__ b_ih, const float* __restrict__ b_hh)
{
    __shared__ __align__(16) unsigned short LB[2 * GRU_M * HDIM];  // [Sl | Hl], 16 KB
    unsigned short* Sl = LB;
    unsigned short* Hl = LB + GRU_M * HDIM;
    __shared__ float Dl[GRU_M];

    int tid = threadIdx.x;
    int i0 = blockIdx.x * GRU_M;

    int srow = tid >> 4;             // 0..31: node-local row
    int cb   = (tid & 15) << 4;      // byte col within 256B row
    int pb   = srow*256 + (cb ^ ((srow & 7) << 4));

    // own rows -> Hl (feeds Wh GEMM + carry)
    *(float4*)((char*)Hl + pb) =
        *(const float4*)((const char*)hb_src + (size_t)(i0 + srow)*256 + cb);

    // row-parallel gather, 4-deep unroll for MLP
    int beg = offs[i0 + srow], end = offs[i0 + srow + 1];
    float acc[8] = {0.f,0.f,0.f,0.f,0.f,0.f,0.f,0.f};
    int e = beg;
    for (; e + 3 < end; e += 4) {
        int s0 = cols[e+0], s1 = cols[e+1], s2 = cols[e+2], s3 = cols[e+3];
        bf16x8 v0 = *(const bf16x8*)((const char*)hb_src + (size_t)s0*256 + cb);
        bf16x8 v1 = *(const bf16x8*)((const char*)hb_src + (size_t)s1*256 + cb);
        bf16x8 v2 = *(const bf16x8*)((const char*)hb_src + (size_t)s2*256 + cb);
        bf16x8 v3 = *(const bf16x8*)((const char*)hb_src + (size_t)s3*256 + cb);
        #pragma unroll
        for (int j = 0; j < 8; ++j) {
            float t0 = bf2f((unsigned short)v0[j]) + bf2f((unsigned short)v1[j]);
            float t1 = bf2f((unsigned short)v2[j]) + bf2f((unsigned short)v3[j]);
            acc[j] += t0 + t1;
        }
    }
    if (e + 1 < end) {
        int s0 = cols[e], s1 = cols[e+1];
        bf16x8 v0 = *(const bf16x8*)((const char*)hb_src + (size_t)s0*256 + cb);
        bf16x8 v1 = *(const bf16x8*)((const char*)hb_src + (size_t)s1*256 + cb);
        #pragma unroll
        for (int j = 0; j < 8; ++j)
            acc[j] += bf2f((unsigned short)v0[j]) + bf2f((unsigned short)v1[j]);
        e += 2;
    }
    if (e < end) {
        bf16x8 v0 = *(const bf16x8*)((const char*)hb_src + (size_t)cols[e]*256 + cb);
        #pragma unroll
        for (int j = 0; j < 8; ++j) acc[j] += bf2f((unsigned short)v0[j]);
    }
    union { ushort2 u2[4]; float4 f4; } pk;
    #pragma unroll
    for (int j = 0; j < 4; ++j) {
        pk.u2[j].x = f2bf(acc[2*j]);
        pk.u2[j].y = f2bf(acc[2*j+1]);
    }
    *(float4*)((char*)Sl + pb) = pk.f4;
    if ((tid & 15) == 0) Dl[srow] = (float)(end - beg);
    __syncthreads();

    int lane = tid & 63;
    int wid  = tid >> 6;       // 0..7 -> col tile
    int kg   = lane >> 4;      // 0..3
    int lr   = lane & 15;
    int c    = (wid << 4) + lr;

    f32x4 a_cr[2], a_cz[2], a_cn[2], a_hr[2], a_hz[2], a_hn[2];
    #pragma unroll
    for (int t = 0; t < 2; ++t) {
        a_cr[t] = (f32x4){0,0,0,0}; a_cz[t] = (f32x4){0,0,0,0}; a_cn[t] = (f32x4){0,0,0,0};
        a_hr[t] = (f32x4){0,0,0,0}; a_hz[t] = (f32x4){0,0,0,0}; a_hn[t] = (f32x4){0,0,0,0};
    }

    int r0 = lr, r1 = 16 + lr;
    int x0 = (r0 & 7) << 4, x1 = (r1 & 7) << 4;

    #pragma unroll
    for (int kc = 0; kc < 4; ++kc) {
        int cbk = kc*64 + kg*16;
        bf16x8 aS0 = *(const bf16x8*)((const char*)Sl + r0*256 + (cbk ^ x0));
        bf16x8 aS1 = *(const bf16x8*)((const char*)Sl + r1*256 + (cbk ^ x1));
        bf16x8 aH0 = *(const bf16x8*)((const char*)Hl + r0*256 + (cbk ^ x0));
        bf16x8 aH1 = *(const bf16x8*)((const char*)Hl + r1*256 + (cbk ^ x1));
        const bf16x8* Bc = (const bf16x8*)Wc + (size_t)kc*1536 + lane;
        const bf16x8* Bh = (const bf16x8*)Wh + (size_t)kc*1536 + lane;
        bf16x8 b;
        b = Bc[(size_t)(wid     ) * 64];
        a_cr[0] = __builtin_amdgcn_mfma_f32_16x16x32_bf16(aS0, b, a_cr[0], 0, 0, 0);
        a_cr[1] = __builtin_amdgcn_mfma_f32_16x16x32_bf16(aS1, b, a_cr[1], 0, 0, 0);
        b = Bc[(size_t)(wid +  8) * 64];
        a_cz[0] = __builtin_amdgcn_mfma_f32_16x16x32_bf16(aS0, b, a_cz[0], 0, 0, 0);
        a_cz[1] = __builtin_amdgcn_mfma_f32_16x16x32_bf16(aS1, b, a_cz[1], 0, 0, 0);
        b = Bc[(size_t)(wid + 16) * 64];
        a_cn[0] = __builtin_amdgcn_mfma_f32_16x16x32_bf16(aS0, b, a_cn[0], 0, 0, 0);
        a_cn[1] = __builtin_amdgcn_mfma_f32_16x16x32_bf16(aS1, b, a_cn[1], 0, 0, 0);
        b = Bh[(size_t)(wid     ) * 64];
        a_hr[0] = __builtin_amdgcn_mfma_f32_16x16x32_bf16(aH0, b, a_hr[0], 0, 0, 0);
        a_hr[1] = __builtin_amdgcn_mfma_f32_16x16x32_bf16(aH1, b, a_hr[1], 0, 0, 0);
        b = Bh[(size_t)(wid +  8) * 64];
        a_hz[0] = __builtin_amdgcn_mfma_f32_16x16x32_bf16(aH0, b, a_hz[0], 0, 0, 0);
        a_hz[1] = __builtin_amdgcn_mfma_f32_16x16x32_bf16(aH1, b, a_hz[1], 0, 0, 0);
        b = Bh[(size_t)(wid + 16) * 64];
        a_hn[0] = __builtin_amdgcn_mfma_f32_16x16x32_bf16(aH0, b, a_hn[0], 0, 0, 0);
        a_hn[1] = __builtin_amdgcn_mfma_f32_16x16x32_bf16(aH1, b, a_hn[1], 0, 0, 0);
    }

    float bc_r = b_c[c],  bc_z = b_c[c+128],  bc_n = b_c[c+256];
    float bs_r = b_ih[c]     + b_hh[c];
    float bs_z = b_ih[c+128] + b_hh[c+128];
    float bi_n = b_ih[c+256], bh_n = b_hh[c+256];

    float hv[2][4];
    #pragma unroll
    for (int t = 0; t < 2; ++t) {
        #pragma unroll
        for (int q = 0; q < 4; ++q) {
            int row = t*16 + (kg << 2) + q;
            float dg = Dl[row];
            float r  = fast_sigmoid(a_cr[t][q] + a_hr[t][q] + fmaf(dg, bc_r, bs_r));
            float z  = fast_sigmoid(a_cz[t][q] + a_hz[t][q] + fmaf(dg, bc_z, bs_z));
            float gin = a_cn[t][q] + fmaf(dg, bc_n, bi_n);
            float ghn = a_hn[t][q] + bh_n;
            float nn = fast_tanh(fmaf(r, ghn, gin));
            float hold = bf2f(*(const unsigned short*)((const char*)Hl + row*256 + ((c*2) ^ ((row & 7) << 4))));
            hv[t][q] = fmaf(z, hold - nn, nn);
        }
    }
    __syncthreads();   // all MFMA/carry reads of Sl,Hl complete before overwrite

    if (!h_out) {
        // bf16 state: stage into Sl (swizzled), then coalesced float4 rows
        #pragma unroll
        for (int t = 0; t < 2; ++t)
            #pragma unroll
            for (int q = 0; q < 4; ++q) {
                int row = t*16 + (kg << 2) + q;
                *(unsigned short*)((char*)Sl + row*256 + ((c*2) ^ ((row & 7) << 4))) = f2bf(hv[t][q]);
            }
        __syncthreads();
        *(float4*)((char*)hb_dst + (size_t)(i0 + srow)*256 + cb) =
            *(const float4*)((const char*)Sl + pb);
    } else {
        // final step: fp32 output only. Stage 32x128 f32 = 16 KB into LB.
        float* F = (float*)LB;
        #pragma unroll
        for (int t = 0; t < 2; ++t)
            #pragma unroll
            for (int q = 0; q < 4; ++q) {
                int row = t*16 + (kg << 2) + q;
                *(float*)((char*)F + row*512 + ((c*4) ^ ((row & 7) << 4))) = hv[t][q];
            }
        __syncthreads();
        int sr2 = tid >> 5;              // 0..15
        int cb2 = (tid & 31) << 4;       // byte within 512B fp32 row
        #pragma unroll
        for (int half = 0; half < 2; ++half) {
            int rr = half*16 + sr2;
            float4 v = *(const float4*)((const char*)F + rr*512 + (cb2 ^ ((rr & 7) << 4)));
            *(float4*)((char*)h_out + (size_t)(i0 + rr)*512 + cb2) = v;
        }
    }
}

extern "C" void kernel_launch(void* const* d_in, const int* in_sizes, int n_in,
                              void* d_out, int out_size, void* d_ws, size_t ws_size,
                              hipStream_t stream)
{
    const float* x     = (const float*)d_in[0];
    const int*   eidx  = (const int*)d_in[1];
    const float* W_msg = (const float*)d_in[2];
    const float* b_msg = (const float*)d_in[3];
    const float* W_ih  = (const float*)d_in[4];
    const float* W_hh  = (const float*)d_in[5];
    const float* b_ih  = (const float*)d_in[6];
    const float* b_hh  = (const float*)d_in[7];

    float* h = (float*)d_out;

    char* ws = (char*)d_ws;
    size_t off = 0;
    auto alloc = [&](size_t bytes) -> void* {
        void* p = ws + off;
        off = (off + bytes + 255) & ~(size_t)255;
        return p;
    };
    unsigned short* hb0 = (unsigned short*)alloc((size_t)N_NODESC*HDIM*sizeof(unsigned short));
    unsigned short* hb1 = (unsigned short*)alloc((size_t)N_NODESC*HDIM*sizeof(unsigned short));
    unsigned short* Wc  = (unsigned short*)alloc((size_t)HDIM*H3*sizeof(unsigned short));
    unsigned short* Wh  = (unsigned short*)alloc((size_t)HDIM*H3*sizeof(unsigned short));
    float* b_c    = (float*)alloc(H3*sizeof(float));
    int*   deg    = (int*)alloc((N_NODESC+1)*sizeof(int));
    int*   offs   = (int*)alloc((N_NODESC+1)*sizeof(int));
    int*   cur    = (int*)alloc(N_NODESC*sizeof(int));
    int*   cols   = (int*)alloc(N_EDGESC*sizeof(int));
    int*   bsums  = (int*)alloc(256*sizeof(int));

    hipMemsetAsync(deg, 0, (N_NODESC+1)*sizeof(int), stream);

    init_hbf<<<(N_NODESC*HDIM/4 + 255)/256, 256, 0, stream>>>(x, hb0);
    prep_pack<<<(HDIM*H3 + 255)/256, 256, 0, stream>>>(W_msg, b_msg, W_ih, W_hh, Wc, Wh, b_c);

    hist_kernel<<<(N_EDGESC + 255)/256, 256, 0, stream>>>(eidx, deg);

    int n_scan = N_NODESC + 1;
    int nb = (n_scan + SCAN_CHUNK - 1) / SCAN_CHUNK;
    scan_partial<<<nb, SCAN_BLOCK, 0, stream>>>(deg, offs, bsums, n_scan);
    scan_sums<<<1, 64, 0, stream>>>(bsums, nb);
    scan_add<<<(n_scan + 255)/256, 256, 0, stream>>>(offs, bsums, n_scan, cur);

    scatter_edges<<<(N_EDGESC + 255)/256, 256, 0, stream>>>(eidx, cur, cols);

    for (int step = 0; step < NUM_STEPSC; ++step) {
        const unsigned short* src = (step & 1) ? hb1 : hb0;
        unsigned short*       dst = (step & 1) ? hb0 : hb1;
        float* out = (step == NUM_STEPSC - 1) ? h : nullptr;
        gnn_step<<<N_NODESC/GRU_M, 512, 0, stream>>>(src, dst, out, offs, cols,
                                                     Wc, Wh, b_c, b_ih, b_hh);
    }
}